// Round 15
// baseline (238.597 us; speedup 1.0000x reference)
//
#include <hip/hip_runtime.h>
#include <hip/hip_bf16.h>

#define TILE_E 32
#define WSTRIDE 132   // fp32 fallback-path stride
#define SB 136        // bf16 tile stride (272 B, 16B-aligned)
#define SF 132        // f32 Y stride (528 B, 16B-aligned)
#define FS 16384      // elems per frag-ordered matrix (128*128)

// frag-matrix slots in ws
#define FRAG_DW2 0
#define FRAG_W1D 1
#define FRAG_CW2 2
#define FRAG_AGT 3
#define FRAG_QW  4
#define FRAG_W1Q 5
#define FRAG_W1C 6
#define FRAG_LIN 7

typedef __attribute__((ext_vector_type(8))) short short8;
typedef __attribute__((ext_vector_type(4))) float f32x4;

__device__ __forceinline__ unsigned short f2bf(float f) {
    __hip_bfloat16 h = __float2bfloat16(f);   // RNE; HW cvt instruction
    unsigned short u; __builtin_memcpy(&u, &h, 2);
    return u;
}

__device__ __forceinline__ float bf2f(unsigned short u) {
    union { unsigned v; float f; } x; x.v = ((unsigned)u) << 16; return x.f;
}

__device__ __forceinline__ f32x4 mfma16(short8 a, short8 b, f32x4 c) {
    return __builtin_amdgcn_mfma_f32_16x16x32_bf16(a, b, c, 0, 0, 0);
}

// Coalesced B-frag load from frag-ordered bf16 matrix (8 x 16B/lane).
__device__ __forceinline__ void load_bfrags_fast(const unsigned short* __restrict__ F,
                                                 int wv, int lane, short8 wB[2][4])
{
#pragma unroll
    for (int cb = 0; cb < 2; ++cb)
#pragma unroll
    for (int kc = 0; kc < 4; ++kc)
        wB[cb][kc] = *(const short8*)(F + ((((wv * 2 + cb) * 4 + kc) * 64 + lane) << 3));
}

// acc[rb][cb] += X(32x128 bf16 tile, stride SB) @ W(regs). 8 A-reads, 16 MFMA.
__device__ __forceinline__ void mfma_gemm32(const unsigned short* __restrict__ X,
                                            const short8 wB[2][4],
                                            f32x4 acc[2][2], int lane)
{
    const int r  = lane & 15;
    const int kg = (lane >> 4) & 3;
#pragma unroll
    for (int rb = 0; rb < 2; ++rb) {
        const unsigned short* xp = X + (rb * 16 + r) * SB + kg * 8;
#pragma unroll
        for (int kc = 0; kc < 4; ++kc) {
            short8 a = *(const short8*)(xp + kc * 32);
            acc[rb][0] = mfma16(a, wB[0][kc], acc[rb][0]);
            acc[rb][1] = mfma16(a, wB[1][kc], acc[rb][1]);
        }
    }
}

// GN core: given 16 per-thread vals (8 threads/row), produce normalized bf16.
__device__ __forceinline__ void gn_core_pack(float vals[16],
                                             const float* __restrict__ gw,
                                             const float* __restrict__ gb,
                                             int c0, short8& o0, short8& o1)
{
    float s1 = 0.f, s2 = 0.f;
#pragma unroll
    for (int i = 0; i < 16; ++i) { s1 += vals[i]; s2 += vals[i] * vals[i]; }
#pragma unroll
    for (int off = 4; off >= 1; off >>= 1) {
        s1 += __shfl_xor(s1, off);
        s2 += __shfl_xor(s2, off);
    }
    float m   = s1 * (1.f / 128.f);
    float var = fmaxf(s2 * (1.f / 128.f) - m * m, 0.f);
    float isc = rsqrtf(var + 1e-5f);
#pragma unroll
    for (int i = 0; i < 16; ++i) {
        float y = fmaxf((vals[i] - m) * isc * gw[c0 + i] + gb[c0 + i], 0.f);
        unsigned short u = f2bf(y);
        if (i < 8) o0[i] = (short)u; else o1[i - 8] = (short)u;
    }
}

// Per-row GN over a 32-row f32 tile (stride SF), relu, bf16 -> dst (vectorized).
__device__ __forceinline__ void gn_row_to_bf16(const float* __restrict__ sY,
                                               const float* __restrict__ gw,
                                               const float* __restrict__ gb,
                                               unsigned short* __restrict__ dst,
                                               int r8, int c0)
{
    const float4* yv = (const float4*)(sY + r8 * SF + c0);
    float4 a = yv[0], b = yv[1], c = yv[2], d = yv[3];
    float vals[16] = { a.x,a.y,a.z,a.w, b.x,b.y,b.z,b.w,
                       c.x,c.y,c.z,c.w, d.x,d.y,d.z,d.w };
    short8 o0, o1;
    gn_core_pack(vals, gw, gb, c0, o0, o1);
    short8* dp = (short8*)(dst + r8 * SB + c0);
    dp[0] = o0; dp[1] = o1;
}

// Same but input tile is bf16 (stride SB), vectorized b128 reads/writes.
__device__ __forceinline__ void gn_bf_to_bf16(const unsigned short* __restrict__ sYb,
                                              const float* __restrict__ gw,
                                              const float* __restrict__ gb,
                                              unsigned short* __restrict__ dst,
                                              int r8, int c0)
{
    const short8* yv = (const short8*)(sYb + r8 * SB + c0);
    short8 a = yv[0], b = yv[1];
    float vals[16];
#pragma unroll
    for (int i = 0; i < 8; ++i) {
        vals[i]     = bf2f((unsigned short)a[i]);
        vals[8 + i] = bf2f((unsigned short)b[i]);
    }
    short8 o0, o1;
    gn_core_pack(vals, gw, gb, c0, o0, o1);
    short8* dp = (short8*)(dst + r8 * SB + c0);
    dp[0] = o0; dp[1] = o1;
}

// ---------------------------------------------------------------------------
// PREP ∪ HIST merged kernel. Blocks [0,512): frag-reorder 8 weight matrices.
// Blocks [512,768): histogram of hi.
// ---------------------------------------------------------------------------
__global__ __launch_bounds__(256) void prep_hist_kernel(
    const float* __restrict__ W0, const float* __restrict__ W1,
    const float* __restrict__ W2, const float* __restrict__ W3,
    const float* __restrict__ W4, const float* __restrict__ W5,
    const float* __restrict__ W6, const float* __restrict__ W7,
    unsigned short* __restrict__ dst,
    const int* __restrict__ hi, int* __restrict__ hist, int E)
{
    const int b = blockIdx.x;
    if (b < 512) {
        int t = b * 256 + threadIdx.x;         // 0 .. 8*FS-1
        int m = t >> 14;
        int e = t & (FS - 1);
        int j    = e & 7;
        int lane = (e >> 3) & 63;
        int kc   = (e >> 9) & 3;
        int cb   = (e >> 11) & 1;
        int wv   = (e >> 12) & 3;
        int k = kc * 32 + ((lane >> 4) & 3) * 8 + j;
        int c = wv * 32 + cb * 16 + (lane & 15);
        const float* W = m == 0 ? W0 : m == 1 ? W1 : m == 2 ? W2 : m == 3 ? W3
                       : m == 4 ? W4 : m == 5 ? W5 : m == 6 ? W6 : W7;
        dst[t] = f2bf(W[k * 128 + c]);
    } else {
        for (int i = (b - 512) * 256 + threadIdx.x; i < E; i += 256 * 256)
            atomicAdd(&hist[hi[i]], 1);
    }
}

// ---------------------------------------------------------------------------
// Single-pass scan: block b reduces hist[0..b*256) for its offset (parallel,
// redundant but cheap: 33 MB total L2 reads), then local chunk prefix.
// ---------------------------------------------------------------------------
__global__ __launch_bounds__(256) void scanBC_kernel(const int* __restrict__ hist,
                                                     int* __restrict__ binCtr,
                                                     int nbins)
{
    __shared__ int part[256];
    __shared__ int red[4];
    __shared__ int coffb;
    const int b = blockIdx.x, t = threadIdx.x;

    int cv = 0;
    const int limit = b * 256;
    for (int i = t; i < limit; i += 256) cv += hist[i];
#pragma unroll
    for (int off = 32; off >= 1; off >>= 1) cv += __shfl_xor(cv, off);
    if ((t & 63) == 0) red[t >> 6] = cv;
    __syncthreads();
    if (t == 0) coffb = red[0] + red[1] + red[2] + red[3];

    int idx = b * 256 + t;
    int v = (idx < nbins) ? hist[idx] : 0;
    part[t] = v;
    __syncthreads();
    for (int off = 1; off < 256; off <<= 1) {
        int p = (t >= off) ? part[t - off] : 0;
        __syncthreads();
        part[t] += p;
        __syncthreads();
    }
    if (idx < nbins) binCtr[idx] = part[t] - v + coffb;
}

// ---------------------------------------------------------------------------
// kq single-tile body: qm_perm = relu(gn(agts@q_w)) @ W1q
// ---------------------------------------------------------------------------
__device__ __forceinline__ void kq_tile_body(
    int tile, const float* __restrict__ agts,
    const float* __restrict__ q_gw, const float* __restrict__ q_gb,
    const unsigned short* __restrict__ frags,
    float* __restrict__ qm, int N,
    unsigned short* sX, float* sY, float* sGw, float* sGb)
{
    const int tid  = threadIdx.x;
    const int lane = tid & 63;
    const int wv   = tid >> 6;
    const int colbase = wv * 32;
    const int r8 = tid >> 3, c0 = (tid & 7) * 16;
    const int cl = lane & 15, rq = lane >> 4;

    short8 wBq[2][4], wB1[2][4];
    load_bfrags_fast(frags + FRAG_QW  * FS, wv, lane, wBq);
    load_bfrags_fast(frags + FRAG_W1Q * FS, wv, lane, wB1);
    if (tid < 128) { sGw[tid] = q_gw[tid]; sGb[tid] = q_gb[tid]; }

    const int base = tile * 32;
    {
        int row = base + r8; if (row >= N) row = N - 1;
        const float* src = agts + (size_t)row * 128 + c0;
        short8 v0, v1;
#pragma unroll
        for (int i = 0; i < 8; ++i) { v0[i] = (short)f2bf(src[i]); v1[i] = (short)f2bf(src[i + 8]); }
        short8* dp = (short8*)(sX + r8 * SB + c0);
        dp[0] = v0; dp[1] = v1;
    }
    __syncthreads();

    f32x4 aQ[2][2] = {{{0,0,0,0},{0,0,0,0}},{{0,0,0,0},{0,0,0,0}}};
    mfma_gemm32(sX, wBq, aQ, lane);
    {
#pragma unroll
        for (int rb = 0; rb < 2; ++rb)
#pragma unroll
        for (int cb = 0; cb < 2; ++cb)
#pragma unroll
        for (int q = 0; q < 4; ++q)
            sY[(rb * 16 + rq * 4 + q) * SF + colbase + cb * 16 + cl] = aQ[rb][cb][q];
    }
    __syncthreads();
    gn_row_to_bf16(sY, sGw, sGb, sX, r8, c0);
    __syncthreads();

    f32x4 aM[2][2] = {{{0,0,0,0},{0,0,0,0}},{{0,0,0,0},{0,0,0,0}}};
    mfma_gemm32(sX, wB1, aM, lane);
#pragma unroll
    for (int rb = 0; rb < 2; ++rb)
#pragma unroll
    for (int q = 0; q < 4; ++q) {
        int row = base + rb * 16 + rq * 4 + q;
        if (row < N) {
            float2 v = make_float2(aM[rb][0][q], aM[rb][1][q]);
            *(float2*)(qm + (size_t)row * 128 + colbase + cl * 2) = v;
        }
    }
}

// kc single-tile body: cm_perm = ctx @ W1c
__device__ __forceinline__ void kc_tile_body(
    int tile, const float* __restrict__ ctx,
    const unsigned short* __restrict__ frags,
    float* __restrict__ cm, int N, unsigned short* sX)
{
    const int tid  = threadIdx.x;
    const int lane = tid & 63;
    const int wv   = tid >> 6;
    const int colbase = wv * 32;
    const int r8 = tid >> 3, c0 = (tid & 7) * 16;
    const int cl = lane & 15, rq = lane >> 4;

    short8 wB[2][4];
    load_bfrags_fast(frags + FRAG_W1C * FS, wv, lane, wB);

    const int base = tile * 32;
    {
        int row = base + r8; if (row >= N) row = N - 1;
        const float* src = ctx + (size_t)row * 128 + c0;
        short8 v0, v1;
#pragma unroll
        for (int i = 0; i < 8; ++i) { v0[i] = (short)f2bf(src[i]); v1[i] = (short)f2bf(src[i + 8]); }
        short8* dp = (short8*)(sX + r8 * SB + c0);
        dp[0] = v0; dp[1] = v1;
    }
    __syncthreads();

    f32x4 acc[2][2] = {{{0,0,0,0},{0,0,0,0}},{{0,0,0,0},{0,0,0,0}}};
    mfma_gemm32(sX, wB, acc, lane);
#pragma unroll
    for (int rb = 0; rb < 2; ++rb)
#pragma unroll
    for (int q = 0; q < 4; ++q) {
        int row = base + rb * 16 + rq * 4 + q;
        if (row < N) {
            float2 v = make_float2(acc[rb][0][q], acc[rb][1][q]);
            *(float2*)(cm + (size_t)row * 128 + colbase + cl * 2) = v;
        }
    }
}

// ---------------------------------------------------------------------------
// SCATTER ∪ KQ ∪ KC merged kernel (scatter hides under node GEMMs).
// Blocks [0,256): scatter -> hiS/wiS/dxS/dyS. [256,+tilesA): kq. Rest: kc.
// ---------------------------------------------------------------------------
__global__ __launch_bounds__(256) void nodes_kernel(
    const int* __restrict__ hi, const int* __restrict__ wi,
    const float* __restrict__ agt_ctrs, const float* __restrict__ ctx_ctrs,
    int* __restrict__ binCtr,
    int* __restrict__ hiS, int* __restrict__ wiS,
    float* __restrict__ dxS, float* __restrict__ dyS,
    const float* __restrict__ agts, const float* __restrict__ ctx,
    const float* __restrict__ q_gw, const float* __restrict__ q_gb,
    const unsigned short* __restrict__ frags,
    float* __restrict__ qm, float* __restrict__ cm,
    int E, int N, int NC, int tilesA)
{
    __shared__ __align__(16) unsigned short sX[32 * SB];
    __shared__ __align__(16) float sY[32 * SF];
    __shared__ float sGw[128], sGb[128];

    const int b = blockIdx.x;
    if (b < 256) {
        for (int i = b * 256 + threadIdx.x; i < E; i += 256 * 256) {
            int h = hi[i], w = wi[i];
            int p = atomicAdd(&binCtr[h], 1);
            hiS[p] = h; wiS[p] = w;
            dxS[p] = agt_ctrs[2 * h]     - ctx_ctrs[2 * w];
            dyS[p] = agt_ctrs[2 * h + 1] - ctx_ctrs[2 * w + 1];
        }
        return;
    }
    int t = b - 256;
    if (t < tilesA)
        kq_tile_body(t, agts, q_gw, q_gb, frags, qm, N, sX, sY, sGw, sGb);
    else
        kc_tile_body(t - tilesA, ctx, frags, cm, NC, sX);
}

// ---------------------------------------------------------------------------
// EDGE (sorted, deferred-W2, bf16 sY, vectorized LDS): 7 barriers/tile.
// launch_bounds MUST stay (256,3): r9 (256,6) and r11 (256,4) both made the
// allocator drop to 40/64 VGPR and spill the weight frags to scratch
// (FETCH 703/394 MB, +60/+50% time). (256,3) -> 84 VGPR, zero spill.
// TILE must stay 32: r13's 64-tile moved qm/cm gathers into the critical
// path (VALUBusy 50->27%, FETCH 2x, edge 120->177 us).
// ---------------------------------------------------------------------------
__global__ __launch_bounds__(256, 3) void edge_sorted_kernel(
    const int* __restrict__ hiS, const int* __restrict__ wiS,
    const float* __restrict__ dxS, const float* __restrict__ dyS,
    const float* __restrict__ dist_w1, const float* __restrict__ dist_b1,
    const float* __restrict__ dist_gw, const float* __restrict__ dist_gb,
    const float* __restrict__ ctx_gw, const float* __restrict__ ctx_gb,
    const unsigned short* __restrict__ frags,
    const float* __restrict__ qm, const float* __restrict__ cm,
    float* __restrict__ msum, int E, int numTiles)
{
    __shared__ __align__(16) unsigned short sH[32 * SB];   // h1 -> d -> m
    __shared__ __align__(16) unsigned short sYb[32 * SB];  // pre-GN bf16
    __shared__ float sW1[3][128];
    __shared__ float sDGw[128], sDGb[128], sCGw[128], sCGb[128];
    __shared__ int sHiA[32], sWiA[32], sKey[33];
    __shared__ float sDx[32], sDy[32];

    const int tid  = threadIdx.x;
    const int lane = tid & 63;
    const int wv   = tid >> 6;
    const int colbase = wv * 32;
    const int r8 = tid >> 3, c0 = (tid & 7) * 16;
    const int cl = lane & 15, rq = lane >> 4;

    short8 wBh[2][4], wBd[2][4];
    load_bfrags_fast(frags + FRAG_DW2 * FS, wv, lane, wBh);
    load_bfrags_fast(frags + FRAG_W1D * FS, wv, lane, wBd);
    if (tid < 128) {
        sW1[0][tid] = dist_w1[tid];
        sW1[1][tid] = dist_w1[128 + tid];
        sW1[2][tid] = dist_b1[tid];
        sDGw[tid] = dist_gw[tid]; sDGb[tid] = dist_gb[tid];
        sCGw[tid] = ctx_gw[tid];  sCGb[tid] = ctx_gb[tid];
    }

    // prefetch regs for the tile about to be processed
    int ph = 0, pw = 0, pkey = -1; float pdx = 0.f, pdy = 0.f;
    if (tid < 32) {
        pkey = -1 - tid;
        int e = blockIdx.x * 32 + tid;
        if (e < E) { ph = hiS[e]; pw = wiS[e]; pkey = ph; pdx = dxS[e]; pdy = dyS[e]; }
    }

    for (int tile = blockIdx.x; tile < numTiles; tile += gridDim.x) {
        __syncthreads();                                   // (a) prev merge done
        if (tid < 32) {
            sHiA[tid] = ph; sWiA[tid] = pw; sKey[tid] = pkey;
            sDx[tid] = pdx; sDy[tid] = pdy;
        }
        __syncthreads();                                   // (b)

        // prefetch NEXT tile's idx (coalesced, consumed next iteration)
        if (tid < 32) {
            pkey = -1 - tid; ph = 0; pw = 0; pdx = 0.f; pdy = 0.f;
            int tn = tile + gridDim.x;
            if (tn < numTiles) {
                int e = tn * 32 + tid;
                if (e < E) { ph = hiS[e]; pw = wiS[e]; pkey = ph; pdx = dxS[e]; pdy = dyS[e]; }
            }
        }

        // gathers of precomputed qm/cm (permuted: float2 = both cb) — issued
        // EARLY so their latency hides under h1 + GEMM1 + GN (r13 lesson).
        float2 gq[2][4], gc[2][4];
#pragma unroll
        for (int rb = 0; rb < 2; ++rb)
#pragma unroll
        for (int q = 0; q < 4; ++q) {
            int r = rb * 16 + rq * 4 + q;
            gq[rb][q] = *(const float2*)(qm + (size_t)sHiA[r] * 128 + colbase + cl * 2);
            gc[rb][q] = *(const float2*)(cm + (size_t)sWiA[r] * 128 + colbase + cl * 2);
        }

        {   // h1 = relu(dctr @ dist_w1 + b1) -> sH bf16 (vectorized write)
            float dx = sDx[r8], dy = sDy[r8];
            short8 o0, o1;
#pragma unroll
            for (int i = 0; i < 16; ++i) {
                int c = c0 + i;
                float v = fmaf(dx, sW1[0][c], fmaf(dy, sW1[1][c], sW1[2][c]));
                unsigned short u = f2bf(fmaxf(v, 0.f));
                if (i < 8) o0[i] = (short)u; else o1[i - 8] = (short)u;
            }
            short8* dp = (short8*)(sH + r8 * SB + c0);
            dp[0] = o0; dp[1] = o1;
        }
        __syncthreads();                                   // (c)

        f32x4 acc[2][2] = {{{0,0,0,0},{0,0,0,0}},{{0,0,0,0},{0,0,0,0}}};
        mfma_gemm32(sH, wBh, acc, lane);
        {
#pragma unroll
            for (int rb = 0; rb < 2; ++rb)
#pragma unroll
            for (int cb = 0; cb < 2; ++cb)
#pragma unroll
            for (int q = 0; q < 4; ++q)
                sYb[(rb * 16 + rq * 4 + q) * SB + colbase + cb * 16 + cl] = f2bf(acc[rb][cb][q]);
        }
        __syncthreads();                                   // (d) sH reads done
        gn_bf_to_bf16(sYb, sDGw, sDGb, sH, r8, c0);        // d -> sH (reuse)
        __syncthreads();                                   // (e)

        f32x4 a2[2][2];
#pragma unroll
        for (int rb = 0; rb < 2; ++rb)
#pragma unroll
        for (int q = 0; q < 4; ++q) {
            a2[rb][0][q] = gq[rb][q].x + gc[rb][q].x;
            a2[rb][1][q] = gq[rb][q].y + gc[rb][q].y;
        }
        mfma_gemm32(sH, wBd, a2, lane);
        {
#pragma unroll
            for (int rb = 0; rb < 2; ++rb)
#pragma unroll
            for (int cb = 0; cb < 2; ++cb)
#pragma unroll
            for (int q = 0; q < 4; ++q)
                sYb[(rb * 16 + rq * 4 + q) * SB + colbase + cb * 16 + cl] = f2bf(a2[rb][cb][q]);
        }
        __syncthreads();                                   // (f) sH reads done
        gn_bf_to_bf16(sYb, sCGw, sCGb, sH, r8, c0);        // m -> sH
        __syncthreads();                                   // (g)

        {   // coalesced segment merge of m (bf16 in sH) into msum[hi]
            const int col   = tid & 127;
            const int rbase = (tid >> 7) * 16;
            float sum = 0.f;
#pragma unroll
            for (int i = 0; i < 16; ++i) {
                int r = rbase + i;
                sum += bf2f(sH[r * SB + col]);
                bool segEnd = (i == 15) || (sKey[r + 1] != sKey[r]);
                if (segEnd) {
                    int key = sKey[r];
                    if (key >= 0) atomicAdd(&msum[(size_t)key * 128 + col], sum);
                    sum = 0.f;
                }
            }
        }
    }
}

// ---------------------------------------------------------------------------
// FINAL (MFMA, 3 GEMMs): acc = agts@agt_w + msum@ctx_w2;
// x = relu(gn(acc)); out = relu(gn(x @ lin_w) + agts). One tile per block.
// ---------------------------------------------------------------------------
__global__ __launch_bounds__(256) void final_mfma_kernel(
    const float* __restrict__ agts, const float* __restrict__ msum,
    const float* __restrict__ norm_w, const float* __restrict__ norm_b,
    const float* __restrict__ lin_gw, const float* __restrict__ lin_gb,
    const unsigned short* __restrict__ frags,
    float* __restrict__ out, int N)
{
    __shared__ __align__(16) unsigned short sXa[32 * SB];
    __shared__ __align__(16) unsigned short sXm[32 * SB];
    __shared__ float sNw[128], sNb[128], sLw[128], sLb[128];

    const int tid  = threadIdx.x;
    const int lane = tid & 63;
    const int wv   = tid >> 6;
    const int colbase = wv * 32;
    const int r8 = tid >> 3, c0 = (tid & 7) * 16;
    const int cl = lane & 15, rq = lane >> 4;

    short8 wBa[2][4], wB2[2][4], wBl[2][4];
    load_bfrags_fast(frags + FRAG_AGT * FS, wv, lane, wBa);
    load_bfrags_fast(frags + FRAG_CW2 * FS, wv, lane, wB2);
    load_bfrags_fast(frags + FRAG_LIN * FS, wv, lane, wBl);
    if (tid < 128) {
        sNw[tid] = norm_w[tid]; sNb[tid] = norm_b[tid];
        sLw[tid] = lin_gw[tid]; sLb[tid] = lin_gb[tid];
    }

    const int base = blockIdx.x * 32;
    {   // stage bf16(agts) -> sXa, bf16(msum) -> sXm
        int row = base + r8; if (row >= N) row = N - 1;
        const float* sa = agts + (size_t)row * 128 + c0;
        const float* sm = msum + (size_t)row * 128 + c0;
        short8 a0, a1, m0, m1;
#pragma unroll
        for (int i = 0; i < 8; ++i) {
            a0[i] = (short)f2bf(sa[i]); a1[i] = (short)f2bf(sa[i + 8]);
            m0[i] = (short)f2bf(sm[i]); m1[i] = (short)f2bf(sm[i + 8]);
        }
        short8* da = (short8*)(sXa + r8 * SB + c0);
        short8* dm = (short8*)(sXm + r8 * SB + c0);
        da[0] = a0; da[1] = a1; dm[0] = m0; dm[1] = m1;
    }
    __syncthreads();

    f32x4 acc[2][2] = {{{0,0,0,0},{0,0,0,0}},{{0,0,0,0},{0,0,0,0}}};
    mfma_gemm32(sXa, wBa, acc, lane);                      // agts @ agt_w
    mfma_gemm32(sXm, wB2, acc, lane);                      // + msum @ ctx_w2
    __syncthreads();                                       // reads of sXa/sXm done
    {
#pragma unroll
        for (int rb = 0; rb < 2; ++rb)
#pragma unroll
        for (int cb = 0; cb < 2; ++cb)
#pragma unroll
        for (int q = 0; q < 4; ++q)
            sXm[(rb * 16 + rq * 4 + q) * SB + colbase + cb * 16 + cl] = f2bf(acc[rb][cb][q]);
    }
    __syncthreads();
    gn_bf_to_bf16(sXm, sNw, sNb, sXa, r8, c0);             // x -> sXa
    __syncthreads();

    f32x4 aL[2][2] = {{{0,0,0,0},{0,0,0,0}},{{0,0,0,0},{0,0,0,0}}};
    mfma_gemm32(sXa, wBl, aL, lane);
    __syncthreads();
    {
#pragma unroll
        for (int rb = 0; rb < 2; ++rb)
#pragma unroll
        for (int cb = 0; cb < 2; ++cb)
#pragma unroll
        for (int q = 0; q < 4; ++q)
            sXm[(rb * 16 + rq * 4 + q) * SB + colbase + cb * 16 + cl] = f2bf(aL[rb][cb][q]);
    }
    __syncthreads();
    {   // gn(lin) + residual + relu -> out (vectorized LDS reads)
        int row = base + r8;
        if (row < N) {
            const short8* yv = (const short8*)(sXm + r8 * SB + c0);
            short8 a = yv[0], b = yv[1];
            float vals[16]; float s1 = 0.f, s2 = 0.f;
#pragma unroll
            for (int i = 0; i < 8; ++i) {
                vals[i]     = bf2f((unsigned short)a[i]);
                vals[8 + i] = bf2f((unsigned short)b[i]);
            }
#pragma unroll
            for (int i = 0; i < 16; ++i) { s1 += vals[i]; s2 += vals[i] * vals[i]; }
#pragma unroll
            for (int off = 4; off >= 1; off >>= 1) {
                s1 += __shfl_xor(s1, off);
                s2 += __shfl_xor(s2, off);
            }
            float m   = s1 * (1.f / 128.f);
            float var = fmaxf(s2 * (1.f / 128.f) - m * m, 0.f);
            float isc = rsqrtf(var + 1e-5f);
            const float* rp = agts + (size_t)row * 128 + c0;
            float* op = out + (size_t)row * 128 + c0;
#pragma unroll
            for (int i = 0; i < 16; ++i) {
                float y = (vals[i] - m) * isc * sLw[c0 + i] + sLb[c0 + i] + rp[i];
                op[i] = fmaxf(y, 0.f);
            }
        }
    }
}

// ---------------------------------------------------------------------------
// fp32 fallback path (round-1 style), used only if workspace too small
// ---------------------------------------------------------------------------
__device__ __forceinline__ void gemm_tile(const float* __restrict__ sX,
                                          const float* __restrict__ sWT,
                                          int lc, int rg,
                                          float acc0[8], float acc1[8])
{
    const float* w0p = sWT + lc * WSTRIDE;
    const float* w1p = sWT + (lc + 64) * WSTRIDE;
    const float* xp  = sX + rg * 8 * WSTRIDE;
#pragma unroll 4
    for (int k = 0; k < 128; k += 4) {
        float4 w0 = *(const float4*)(w0p + k);
        float4 w1 = *(const float4*)(w1p + k);
#pragma unroll
        for (int j = 0; j < 8; ++j) {
            float4 x = *(const float4*)(xp + j * WSTRIDE + k);
            acc0[j] = fmaf(x.x, w0.x, acc0[j]);
            acc0[j] = fmaf(x.y, w0.y, acc0[j]);
            acc0[j] = fmaf(x.z, w0.z, acc0[j]);
            acc0[j] = fmaf(x.w, w0.w, acc0[j]);
            acc1[j] = fmaf(x.x, w1.x, acc1[j]);
            acc1[j] = fmaf(x.y, w1.y, acc1[j]);
            acc1[j] = fmaf(x.z, w1.z, acc1[j]);
            acc1[j] = fmaf(x.w, w1.w, acc1[j]);
        }
    }
}

__device__ __forceinline__ void stage_wt(const float* __restrict__ W,
                                         float* __restrict__ sWT, int tid)
{
    const int c  = tid & 127;
    const int k0 = tid >> 7;
    float*       dst = sWT + c * WSTRIDE + k0;
    const float* src = W + tid;
    float v[16];
#pragma unroll
    for (int p = 0; p < 4; ++p) {
#pragma unroll
        for (int i = 0; i < 16; ++i) v[i] = src[(p * 16 + i) * 256];
#pragma unroll
        for (int i = 0; i < 16; ++i) dst[(p * 16 + i) * 2] = v[i];
    }
}

__device__ __forceinline__ void gn_rows_lds(const float acc0[8], const float acc1[8],
                                            float gw0, float gw1, float gb0, float gb1,
                                            bool relu, float* __restrict__ dst,
                                            int lc, int rg)
{
#pragma unroll
    for (int j = 0; j < 8; ++j) {
        float s1 = acc0[j] + acc1[j];
        float s2 = acc0[j] * acc0[j] + acc1[j] * acc1[j];
#pragma unroll
        for (int off = 32; off >= 1; off >>= 1) {
            s1 += __shfl_xor(s1, off);
            s2 += __shfl_xor(s2, off);
        }
        float m   = s1 * (1.f / 128.f);
        float var = fmaxf(s2 * (1.f / 128.f) - m * m, 0.f);
        float isc = rsqrtf(var + 1e-5f);
        float y0  = (acc0[j] - m) * isc * gw0 + gb0;
        float y1  = (acc1[j] - m) * isc * gw1 + gb1;
        if (relu) { y0 = fmaxf(y0, 0.f); y1 = fmaxf(y1, 0.f); }
        int r = rg * 8 + j;
        dst[r * WSTRIDE + lc]      = y0;
        dst[r * WSTRIDE + lc + 64] = y1;
    }
}

__global__ __launch_bounds__(256) void rowgemm_kernel(
    const float* __restrict__ X, const float* __restrict__ W,
    float* __restrict__ Y, int n)
{
    __shared__ float sWT[128 * WSTRIDE];
    __shared__ float sX[TILE_E * WSTRIDE];
    const int tid  = threadIdx.x;
    const int base = blockIdx.x * TILE_E;
    {
        int r = tid >> 3, c0 = (tid & 7) * 16;
        int row = base + r;
        if (row < n) {
            const float* src = X + (size_t)row * 128 + c0;
            float*       dst = sX + r * WSTRIDE + c0;
#pragma unroll
            for (int i = 0; i < 4; ++i)
                *(float4*)(dst + i * 4) = *(const float4*)(src + i * 4);
        }
    }
    stage_wt(W, sWT, tid);
    __syncthreads();
    const int lc = tid & 63, rg = tid >> 6;
    float acc0[8] = {0,0,0,0,0,0,0,0}, acc1[8] = {0,0,0,0,0,0,0,0};
    gemm_tile(sX, sWT, lc, rg, acc0, acc1);
#pragma unroll
    for (int j = 0; j < 8; ++j) {
        int row = base + rg * 8 + j;
        if (row < n) {
            Y[(size_t)row * 128 + lc]      = acc0[j];
            Y[(size_t)row * 128 + lc + 64] = acc1[j];
        }
    }
}

__global__ __launch_bounds__(256) void edge_kernel(
    const float* __restrict__ agt_ctrs, const float* __restrict__ ctx_ctrs,
    const int* __restrict__ hi, const int* __restrict__ wi,
    const float* __restrict__ qsrc, const float* __restrict__ ctx,
    const float* __restrict__ dist_w1, const float* __restrict__ dist_b1,
    const float* __restrict__ dist_w2,
    const float* __restrict__ dist_gw, const float* __restrict__ dist_gb,
    const float* __restrict__ q_w,
    const float* __restrict__ q_gw, const float* __restrict__ q_gb,
    const float* __restrict__ ctx_w1,
    const float* __restrict__ ctx_gw, const float* __restrict__ ctx_gb,
    const float* __restrict__ ctx_w2,
    float* __restrict__ out, int E, int numTiles)
{
    __shared__ float sWT[128 * WSTRIDE];
    __shared__ float sH2[TILE_E * WSTRIDE];
    __shared__ float sD2[TILE_E * WSTRIDE];
    __shared__ float sQ2[TILE_E * WSTRIDE];
    __shared__ float sC2[TILE_E * WSTRIDE];
    __shared__ int   sHi[TILE_E];
    __shared__ int   sWiB[TILE_E];
    __shared__ float sDx2[TILE_E], sDy2[TILE_E];

    const int tid = threadIdx.x;
    const int lc = tid & 63, rg = tid >> 6;

    const float dgw0 = dist_gw[lc], dgw1 = dist_gw[lc + 64];
    const float dgb0 = dist_gb[lc], dgb1 = dist_gb[lc + 64];
    const float cgw0 = ctx_gw[lc],  cgw1 = ctx_gw[lc + 64];
    const float cgb0 = ctx_gb[lc],  cgb1 = ctx_gb[lc + 64];
    const float qgw0 = q_gw[lc], qgw1 = q_gw[lc + 64];
    const float qgb0 = q_gb[lc], qgb1 = q_gb[lc + 64];
    const int   hc  = tid & 127;
    const int   hrg = tid >> 7;
    const float w1x = dist_w1[hc], w1y = dist_w1[128 + hc], b1c = dist_b1[hc];

    for (int tile = blockIdx.x; tile < numTiles; tile += gridDim.x) {
        const int base = tile * TILE_E;
        __syncthreads();
        if (tid < TILE_E) {
            int e = base + tid;
            int h = 0, w = 0;
            if (e < E) { h = hi[e]; w = wi[e]; }
            sHi[tid]  = h;
            sWiB[tid] = w;
            sDx2[tid] = agt_ctrs[2 * h]     - ctx_ctrs[2 * w];
            sDy2[tid] = agt_ctrs[2 * h + 1] - ctx_ctrs[2 * w + 1];
        }
        __syncthreads();
        {
            int r = tid >> 3, c0 = (tid & 7) * 16;
            int h = sHi[r], w = sWiB[r];
            const float* qs = qsrc + (size_t)h * 128 + c0;
            const float* cs = ctx  + (size_t)w * 128 + c0;
            float* qd = sQ2 + r * WSTRIDE + c0;
            float* cd = sC2 + r * WSTRIDE + c0;
#pragma unroll
            for (int i = 0; i < 4; ++i) {
                *(float4*)(qd + i * 4) = *(const float4*)(qs + i * 4);
                *(float4*)(cd + i * 4) = *(const float4*)(cs + i * 4);
            }
        }
        {
#pragma unroll
            for (int j = 0; j < 16; ++j) {
                int r = hrg * 16 + j;
                float v = fmaf(sDx2[r], w1x, fmaf(sDy2[r], w1y, b1c));
                sH2[r * WSTRIDE + hc] = fmaxf(v, 0.f);
            }
        }
        __syncthreads();
        stage_wt(q_w, sWT, tid);
        __syncthreads();
        {
            float a0[8] = {0,0,0,0,0,0,0,0}, a1[8] = {0,0,0,0,0,0,0,0};
            gemm_tile(sQ2, sWT, lc, rg, a0, a1);
            __syncthreads();
            gn_rows_lds(a0, a1, qgw0, qgw1, qgb0, qgb1, true, sQ2, lc, rg);
        }
        __syncthreads();
        stage_wt(dist_w2, sWT, tid);
        __syncthreads();
        {
            float a0[8] = {0,0,0,0,0,0,0,0}, a1[8] = {0,0,0,0,0,0,0,0};
            gemm_tile(sH2, sWT, lc, rg, a0, a1);
            gn_rows_lds(a0, a1, dgw0, dgw1, dgb0, dgb1, true, sD2, lc, rg);
        }
        float m0[8] = {0,0,0,0,0,0,0,0}, m1[8] = {0,0,0,0,0,0,0,0};
        __syncthreads();
        stage_wt(ctx_w1, sWT, tid);
        __syncthreads();
        gemm_tile(sD2, sWT, lc, rg, m0, m1);
        __syncthreads();
        stage_wt(ctx_w1 + 128 * 128, sWT, tid);
        __syncthreads();
        gemm_tile(sQ2, sWT, lc, rg, m0, m1);
        __syncthreads();
        stage_wt(ctx_w1 + 2 * 128 * 128, sWT, tid);
        __syncthreads();
        gemm_tile(sC2, sWT, lc, rg, m0, m1);
        gn_rows_lds(m0, m1, cgw0, cgw1, cgb0, cgb1, true, sH2, lc, rg);
        __syncthreads();
        stage_wt(ctx_w2, sWT, tid);
        __syncthreads();
        {
            float a0[8] = {0,0,0,0,0,0,0,0}, a1[8] = {0,0,0,0,0,0,0,0};
            gemm_tile(sH2, sWT, lc, rg, a0, a1);
#pragma unroll
            for (int j = 0; j < 8; ++j) {
                int r = rg * 8 + j;
                int e = base + r;
                if (e < E) {
                    int h = sHi[r];
                    atomicAdd(&out[(size_t)h * 128 + lc],      a0[j]);
                    atomicAdd(&out[(size_t)h * 128 + lc + 64], a1[j]);
                }
            }
        }
    }
}

__global__ __launch_bounds__(256) void final_kernel(
    const float* __restrict__ agts,
    const float* __restrict__ norm_w, const float* __restrict__ norm_b,
    const float* __restrict__ lin_w,
    const float* __restrict__ lin_gw, const float* __restrict__ lin_gb,
    float* __restrict__ out, int n)
{
    __shared__ float sWT[128 * WSTRIDE];
    __shared__ float sX[TILE_E * WSTRIDE];
    const int tid  = threadIdx.x;
    const int base = blockIdx.x * TILE_E;
    {
        int r = tid >> 3, c0 = (tid & 7) * 16;
        int row = base + r;
        if (row < n) {
            const float* src = out + (size_t)row * 128 + c0;
            float vals[16];
            float s1 = 0.f, s2 = 0.f;
#pragma unroll
            for (int i = 0; i < 16; ++i) {
                float v = src[i];
                vals[i] = v; s1 += v; s2 += v * v;
            }
#pragma unroll
            for (int off = 4; off >= 1; off >>= 1) {
                s1 += __shfl_xor(s1, off);
                s2 += __shfl_xor(s2, off);
            }
            float m   = s1 * (1.f / 128.f);
            float var = fmaxf(s2 * (1.f / 128.f) - m * m, 0.f);
            float isc = rsqrtf(var + 1e-5f);
            float* dst = sX + r * WSTRIDE + c0;
#pragma unroll
            for (int i = 0; i < 16; ++i) {
                int c = c0 + i;
                float y = (vals[i] - m) * isc * norm_w[c] + norm_b[c];
                dst[i] = fmaxf(y, 0.f);
            }
        }
    }
    stage_wt(lin_w, sWT, tid);
    __syncthreads();
    const int lc = tid & 63, rg = tid >> 6;
    float acc0[8] = {0,0,0,0,0,0,0,0}, acc1[8] = {0,0,0,0,0,0,0,0};
    gemm_tile(sX, sWT, lc, rg, acc0, acc1);
    const float lgw0 = lin_gw[lc], lgw1 = lin_gw[lc + 64];
    const float lgb0 = lin_gb[lc], lgb1 = lin_gb[lc + 64];
#pragma unroll
    for (int j = 0; j < 8; ++j) {
        float s1 = acc0[j] + acc1[j];
        float s2 = acc0[j] * acc0[j] + acc1[j] * acc1[j];
#pragma unroll
        for (int off = 32; off >= 1; off >>= 1) {
            s1 += __shfl_xor(s1, off);
            s2 += __shfl_xor(s2, off);
        }
        float m   = s1 * (1.f / 128.f);
        float var = fmaxf(s2 * (1.f / 128.f) - m * m, 0.f);
        float isc = rsqrtf(var + 1e-5f);
        int row = base + rg * 8 + j;
        if (row < n) {
            size_t ro = (size_t)row * 128;
            float y0 = (acc0[j] - m) * isc * lgw0 + lgb0 + agts[ro + lc];
            float y1 = (acc1[j] - m) * isc * lgw1 + lgb1 + agts[ro + lc + 64];
            out[ro + lc]      = fmaxf(y0, 0.f);
            out[ro + lc + 64] = fmaxf(y1, 0.f);
        }
    }
}

// ---------------------------------------------------------------------------
extern "C" void kernel_launch(void* const* d_in, const int* in_sizes, int n_in,
                              void* d_out, int out_size, void* d_ws, size_t ws_size,
                              hipStream_t stream)
{
    const float* agts     = (const float*)d_in[0];
    const float* ctx      = (const float*)d_in[1];
    const float* agt_ctrs = (const float*)d_in[2];
    const float* ctx_ctrs = (const float*)d_in[3];
    const int*   hi       = (const int*)d_in[4];
    const int*   wi       = (const int*)d_in[5];
    const float* dist_w1  = (const float*)d_in[6];
    const float* dist_b1  = (const float*)d_in[7];
    const float* dist_w2  = (const float*)d_in[8];
    const float* dist_gw  = (const float*)d_in[9];
    const float* dist_gb  = (const float*)d_in[10];
    const float* q_w      = (const float*)d_in[11];
    const float* q_gw     = (const float*)d_in[12];
    const float* q_gb     = (const float*)d_in[13];
    const float* ctx_w1   = (const float*)d_in[14];
    const float* ctx_gw   = (const float*)d_in[15];
    const float* ctx_gb   = (const float*)d_in[16];
    const float* ctx_w2   = (const float*)d_in[17];
    const float* agt_w    = (const float*)d_in[18];
    const float* norm_w   = (const float*)d_in[19];
    const float* norm_b   = (const float*)d_in[20];
    const float* lin_w    = (const float*)d_in[21];
    const float* lin_gw   = (const float*)d_in[22];
    const float* lin_gb   = (const float*)d_in[23];

    const int N  = in_sizes[0] / 128;   // agents (= bins)
    const int NC = in_sizes[1] / 128;   // ctx nodes
    const int E  = in_sizes[4];
    float* out = (float*)d_out;

    const int tilesA   = (N + 31) / 32;
    const int tilesC   = (NC + 31) / 32;
    const int numTiles = (E + 31) / 32;
    const int nchunks  = (N + 255) / 256;

    const size_t needQM = (size_t)N  * 128 * sizeof(float);
    const size_t needCM = (size_t)NC * 128 * sizeof(float);
    const size_t needMS = (size_t)N  * 128 * sizeof(float);
    const size_t needH  = (size_t)N * sizeof(int);
    const size_t needB  = (size_t)N * sizeof(int);
    const size_t needE4 = (size_t)E * sizeof(int);   // each of hiS/wiS/dxS/dyS
    const size_t needF  = (size_t)8 * FS * sizeof(unsigned short);
    const size_t needTotal = needQM + needCM + needMS + needH + needB
                           + 4 * needE4 + needF;

    if (ws_size >= needTotal && nchunks <= 256) {
        char* w = (char*)d_ws;
        float*          qm     = (float*)w;            w += needQM;
        float*          cm     = (float*)w;            w += needCM;
        float*          msum   = (float*)w;            w += needMS;   // zeroed
        int*            hist   = (int*)w;              w += needH;    // zeroed
        int*            binCtr = (int*)w;              w += needB;
        int*            hiS    = (int*)w;              w += needE4;
        int*            wiS    = (int*)w;              w += needE4;
        float*          dxS    = (float*)w;            w += needE4;
        float*          dyS    = (float*)w;            w += needE4;
        unsigned short* fragsW = (unsigned short*)w;   w += needF;

        // one memset covers msum + hist (adjacent)
        hipMemsetAsync(msum, 0, needMS + needH, stream);

        // L1: prep frags (512 blocks) ∪ hist (256 blocks)
        prep_hist_kernel<<<768, 256, 0, stream>>>(
            dist_w2, ctx_w1, ctx_w2, agt_w, q_w,
            ctx_w1 + 128 * 128, ctx_w1 + 2 * 128 * 128, lin_w, fragsW,
            hi, hist, E);

        // L2: single-pass scan (per-block direct offset reduction)
        scanBC_kernel<<<nchunks, 256, 0, stream>>>(hist, binCtr, N);

        // L3: scatter (256, hidden under node GEMMs) ∪ kq (tilesA) ∪ kc (tilesC)
        nodes_kernel<<<256 + tilesA + tilesC, 256, 0, stream>>>(
            hi, wi, agt_ctrs, ctx_ctrs, binCtr, hiS, wiS, dxS, dyS,
            agts, ctx, q_gw, q_gb, fragsW, qm, cm,
            E, N, NC, tilesA);

        // L4: edge pipeline over sorted edges -> msum (grid = exact residency)
        int gridE = numTiles < 768 ? numTiles : 768;
        edge_sorted_kernel<<<gridE, 256, 0, stream>>>(
            hiS, wiS, dxS, dyS,
            dist_w1, dist_b1, dist_gw, dist_gb, ctx_gw, ctx_gb,
            fragsW, qm, cm, msum, E, numTiles);

        // L5: final: agts@agt_w + msum@W2 -> norms -> out
        final_mfma_kernel<<<tilesA, 256, 0, stream>>>(
            agts, msum, norm_w, norm_b, lin_gw, lin_gb, fragsW, out, N);
    } else {
        // fp32 fallback (no workspace needed)
        rowgemm_kernel<<<tilesA, 256, 0, stream>>>(agts, agt_w, out, N);
        int gridE = numTiles < 8192 ? numTiles : 8192;
        edge_kernel<<<gridE, 256, 0, stream>>>(agt_ctrs, ctx_ctrs, hi, wi,
            agts, ctx,
            dist_w1, dist_b1, dist_w2, dist_gw, dist_gb,
            q_w, q_gw, q_gb,
            ctx_w1, ctx_gw, ctx_gb, ctx_w2,
            out, E, numTiles);
        final_kernel<<<tilesA, 256, 0, stream>>>(agts, norm_w, norm_b,
            lin_w, lin_gw, lin_gb, out, N);
    }
}

// Round 16
// 208.998 us; speedup vs baseline: 1.1416x; 1.1416x over previous
//
#include <hip/hip_runtime.h>
#include <hip/hip_bf16.h>

#define TILE_E 32
#define WSTRIDE 132   // fp32 fallback-path stride
#define SB 136        // bf16 tile stride (272 B, 16B-aligned)
#define SF 132        // f32 Y stride (528 B, 16B-aligned)
#define FS 16384      // elems per frag-ordered matrix (128*128)

// frag-matrix slots in ws
#define FRAG_DW2 0
#define FRAG_W1D 1
#define FRAG_CW2 2
#define FRAG_AGT 3
#define FRAG_QW  4
#define FRAG_W1Q 5
#define FRAG_W1C 6
#define FRAG_LIN 7

typedef __attribute__((ext_vector_type(8))) short short8;
typedef __attribute__((ext_vector_type(4))) float f32x4;

__device__ __forceinline__ unsigned short f2bf(float f) {
    __hip_bfloat16 h = __float2bfloat16(f);   // RNE; HW cvt instruction
    unsigned short u; __builtin_memcpy(&u, &h, 2);
    return u;
}

__device__ __forceinline__ float bf2f(unsigned short u) {
    union { unsigned v; float f; } x; x.v = ((unsigned)u) << 16; return x.f;
}

__device__ __forceinline__ f32x4 mfma16(short8 a, short8 b, f32x4 c) {
    return __builtin_amdgcn_mfma_f32_16x16x32_bf16(a, b, c, 0, 0, 0);
}

// Coalesced B-frag load from frag-ordered bf16 matrix (8 x 16B/lane).
__device__ __forceinline__ void load_bfrags_fast(const unsigned short* __restrict__ F,
                                                 int wv, int lane, short8 wB[2][4])
{
#pragma unroll
    for (int cb = 0; cb < 2; ++cb)
#pragma unroll
    for (int kc = 0; kc < 4; ++kc)
        wB[cb][kc] = *(const short8*)(F + ((((wv * 2 + cb) * 4 + kc) * 64 + lane) << 3));
}

// acc[rb][cb] += X(32x128 bf16 tile, stride SB) @ W(regs). 8 A-reads, 16 MFMA.
__device__ __forceinline__ void mfma_gemm32(const unsigned short* __restrict__ X,
                                            const short8 wB[2][4],
                                            f32x4 acc[2][2], int lane)
{
    const int r  = lane & 15;
    const int kg = (lane >> 4) & 3;
#pragma unroll
    for (int rb = 0; rb < 2; ++rb) {
        const unsigned short* xp = X + (rb * 16 + r) * SB + kg * 8;
#pragma unroll
        for (int kc = 0; kc < 4; ++kc) {
            short8 a = *(const short8*)(xp + kc * 32);
            acc[rb][0] = mfma16(a, wB[0][kc], acc[rb][0]);
            acc[rb][1] = mfma16(a, wB[1][kc], acc[rb][1]);
        }
    }
}

// GN core: given 16 per-thread vals (8 threads/row), produce normalized bf16.
__device__ __forceinline__ void gn_core_pack(float vals[16],
                                             const float* __restrict__ gw,
                                             const float* __restrict__ gb,
                                             int c0, short8& o0, short8& o1)
{
    float s1 = 0.f, s2 = 0.f;
#pragma unroll
    for (int i = 0; i < 16; ++i) { s1 += vals[i]; s2 += vals[i] * vals[i]; }
#pragma unroll
    for (int off = 4; off >= 1; off >>= 1) {
        s1 += __shfl_xor(s1, off);
        s2 += __shfl_xor(s2, off);
    }
    float m   = s1 * (1.f / 128.f);
    float var = fmaxf(s2 * (1.f / 128.f) - m * m, 0.f);
    float isc = rsqrtf(var + 1e-5f);
#pragma unroll
    for (int i = 0; i < 16; ++i) {
        float y = fmaxf((vals[i] - m) * isc * gw[c0 + i] + gb[c0 + i], 0.f);
        unsigned short u = f2bf(y);
        if (i < 8) o0[i] = (short)u; else o1[i - 8] = (short)u;
    }
}

// Per-row GN over a 32-row f32 tile (stride SF), relu, bf16 -> dst (vectorized).
__device__ __forceinline__ void gn_row_to_bf16(const float* __restrict__ sY,
                                               const float* __restrict__ gw,
                                               const float* __restrict__ gb,
                                               unsigned short* __restrict__ dst,
                                               int r8, int c0)
{
    const float4* yv = (const float4*)(sY + r8 * SF + c0);
    float4 a = yv[0], b = yv[1], c = yv[2], d = yv[3];
    float vals[16] = { a.x,a.y,a.z,a.w, b.x,b.y,b.z,b.w,
                       c.x,c.y,c.z,c.w, d.x,d.y,d.z,d.w };
    short8 o0, o1;
    gn_core_pack(vals, gw, gb, c0, o0, o1);
    short8* dp = (short8*)(dst + r8 * SB + c0);
    dp[0] = o0; dp[1] = o1;
}

// Same but input tile is bf16 (stride SB), vectorized b128 reads/writes.
__device__ __forceinline__ void gn_bf_to_bf16(const unsigned short* __restrict__ sYb,
                                              const float* __restrict__ gw,
                                              const float* __restrict__ gb,
                                              unsigned short* __restrict__ dst,
                                              int r8, int c0)
{
    const short8* yv = (const short8*)(sYb + r8 * SB + c0);
    short8 a = yv[0], b = yv[1];
    float vals[16];
#pragma unroll
    for (int i = 0; i < 8; ++i) {
        vals[i]     = bf2f((unsigned short)a[i]);
        vals[8 + i] = bf2f((unsigned short)b[i]);
    }
    short8 o0, o1;
    gn_core_pack(vals, gw, gb, c0, o0, o1);
    short8* dp = (short8*)(dst + r8 * SB + c0);
    dp[0] = o0; dp[1] = o1;
}

// ---------------------------------------------------------------------------
// PREP ∪ HIST merged kernel. Blocks [0,512): frag-reorder 8 weight matrices.
// Blocks [512,768): histogram of hi.
// ---------------------------------------------------------------------------
__global__ __launch_bounds__(256) void prep_hist_kernel(
    const float* __restrict__ W0, const float* __restrict__ W1,
    const float* __restrict__ W2, const float* __restrict__ W3,
    const float* __restrict__ W4, const float* __restrict__ W5,
    const float* __restrict__ W6, const float* __restrict__ W7,
    unsigned short* __restrict__ dst,
    const int* __restrict__ hi, int* __restrict__ hist, int E)
{
    const int b = blockIdx.x;
    if (b < 512) {
        int t = b * 256 + threadIdx.x;         // 0 .. 8*FS-1
        int m = t >> 14;
        int e = t & (FS - 1);
        int j    = e & 7;
        int lane = (e >> 3) & 63;
        int kc   = (e >> 9) & 3;
        int cb   = (e >> 11) & 1;
        int wv   = (e >> 12) & 3;
        int k = kc * 32 + ((lane >> 4) & 3) * 8 + j;
        int c = wv * 32 + cb * 16 + (lane & 15);
        const float* W = m == 0 ? W0 : m == 1 ? W1 : m == 2 ? W2 : m == 3 ? W3
                       : m == 4 ? W4 : m == 5 ? W5 : m == 6 ? W6 : W7;
        dst[t] = f2bf(W[k * 128 + c]);
    } else {
        for (int i = (b - 512) * 256 + threadIdx.x; i < E; i += 256 * 256)
            atomicAdd(&hist[hi[i]], 1);
    }
}

// ---------------------------------------------------------------------------
// Parallel scan: A = per-chunk sums; BC = per-chunk prefix with local coff.
// ---------------------------------------------------------------------------
__global__ __launch_bounds__(256) void scanA_kernel(const int* __restrict__ hist,
                                                    int* __restrict__ csum, int nbins)
{
    __shared__ int red[4];
    int b = blockIdx.x;
    int idx = b * 256 + threadIdx.x;
    int v = (idx < nbins) ? hist[idx] : 0;
#pragma unroll
    for (int off = 32; off >= 1; off >>= 1) v += __shfl_xor(v, off);
    if ((threadIdx.x & 63) == 0) red[threadIdx.x >> 6] = v;
    __syncthreads();
    if (threadIdx.x == 0) csum[b] = red[0] + red[1] + red[2] + red[3];
}

// Each block b: coff_b = sum csum[0..b-1] (local reduce), then chunk prefix.
__global__ __launch_bounds__(256) void scanBC_kernel(const int* __restrict__ hist,
                                                     const int* __restrict__ csum,
                                                     int* __restrict__ binCtr,
                                                     int nbins, int nchunks)
{
    __shared__ int part[256];
    __shared__ int red[4];
    __shared__ int coffb;
    const int b = blockIdx.x, t = threadIdx.x;

    int cv = (t < b && t < nchunks) ? csum[t] : 0;
#pragma unroll
    for (int off = 32; off >= 1; off >>= 1) cv += __shfl_xor(cv, off);
    if ((t & 63) == 0) red[t >> 6] = cv;
    __syncthreads();
    if (t == 0) coffb = red[0] + red[1] + red[2] + red[3];

    int idx = b * 256 + t;
    int v = (idx < nbins) ? hist[idx] : 0;
    part[t] = v;
    __syncthreads();
    for (int off = 1; off < 256; off <<= 1) {
        int p = (t >= off) ? part[t - off] : 0;
        __syncthreads();
        part[t] += p;
        __syncthreads();
    }
    if (idx < nbins) binCtr[idx] = part[t] - v + coffb;
}

// ---------------------------------------------------------------------------
// kq single-tile body: qm_perm = relu(gn(agts@q_w)) @ W1q
// ---------------------------------------------------------------------------
__device__ __forceinline__ void kq_tile_body(
    int tile, const float* __restrict__ agts,
    const float* __restrict__ q_gw, const float* __restrict__ q_gb,
    const unsigned short* __restrict__ frags,
    float* __restrict__ qm, int N,
    unsigned short* sX, float* sY, float* sGw, float* sGb)
{
    const int tid  = threadIdx.x;
    const int lane = tid & 63;
    const int wv   = tid >> 6;
    const int colbase = wv * 32;
    const int r8 = tid >> 3, c0 = (tid & 7) * 16;
    const int cl = lane & 15, rq = lane >> 4;

    short8 wBq[2][4], wB1[2][4];
    load_bfrags_fast(frags + FRAG_QW  * FS, wv, lane, wBq);
    load_bfrags_fast(frags + FRAG_W1Q * FS, wv, lane, wB1);
    if (tid < 128) { sGw[tid] = q_gw[tid]; sGb[tid] = q_gb[tid]; }

    const int base = tile * 32;
    {
        int row = base + r8; if (row >= N) row = N - 1;
        const float* src = agts + (size_t)row * 128 + c0;
        short8 v0, v1;
#pragma unroll
        for (int i = 0; i < 8; ++i) { v0[i] = (short)f2bf(src[i]); v1[i] = (short)f2bf(src[i + 8]); }
        short8* dp = (short8*)(sX + r8 * SB + c0);
        dp[0] = v0; dp[1] = v1;
    }
    __syncthreads();

    f32x4 aQ[2][2] = {{{0,0,0,0},{0,0,0,0}},{{0,0,0,0},{0,0,0,0}}};
    mfma_gemm32(sX, wBq, aQ, lane);
    {
#pragma unroll
        for (int rb = 0; rb < 2; ++rb)
#pragma unroll
        for (int cb = 0; cb < 2; ++cb)
#pragma unroll
        for (int q = 0; q < 4; ++q)
            sY[(rb * 16 + rq * 4 + q) * SF + colbase + cb * 16 + cl] = aQ[rb][cb][q];
    }
    __syncthreads();
    gn_row_to_bf16(sY, sGw, sGb, sX, r8, c0);
    __syncthreads();

    f32x4 aM[2][2] = {{{0,0,0,0},{0,0,0,0}},{{0,0,0,0},{0,0,0,0}}};
    mfma_gemm32(sX, wB1, aM, lane);
#pragma unroll
    for (int rb = 0; rb < 2; ++rb)
#pragma unroll
    for (int q = 0; q < 4; ++q) {
        int row = base + rb * 16 + rq * 4 + q;
        if (row < N) {
            float2 v = make_float2(aM[rb][0][q], aM[rb][1][q]);
            *(float2*)(qm + (size_t)row * 128 + colbase + cl * 2) = v;
        }
    }
}

// kc single-tile body: cm_perm = ctx @ W1c
__device__ __forceinline__ void kc_tile_body(
    int tile, const float* __restrict__ ctx,
    const unsigned short* __restrict__ frags,
    float* __restrict__ cm, int N, unsigned short* sX)
{
    const int tid  = threadIdx.x;
    const int lane = tid & 63;
    const int wv   = tid >> 6;
    const int colbase = wv * 32;
    const int r8 = tid >> 3, c0 = (tid & 7) * 16;
    const int cl = lane & 15, rq = lane >> 4;

    short8 wB[2][4];
    load_bfrags_fast(frags + FRAG_W1C * FS, wv, lane, wB);

    const int base = tile * 32;
    {
        int row = base + r8; if (row >= N) row = N - 1;
        const float* src = ctx + (size_t)row * 128 + c0;
        short8 v0, v1;
#pragma unroll
        for (int i = 0; i < 8; ++i) { v0[i] = (short)f2bf(src[i]); v1[i] = (short)f2bf(src[i + 8]); }
        short8* dp = (short8*)(sX + r8 * SB + c0);
        dp[0] = v0; dp[1] = v1;
    }
    __syncthreads();

    f32x4 acc[2][2] = {{{0,0,0,0},{0,0,0,0}},{{0,0,0,0},{0,0,0,0}}};
    mfma_gemm32(sX, wB, acc, lane);
#pragma unroll
    for (int rb = 0; rb < 2; ++rb)
#pragma unroll
    for (int q = 0; q < 4; ++q) {
        int row = base + rb * 16 + rq * 4 + q;
        if (row < N) {
            float2 v = make_float2(acc[rb][0][q], acc[rb][1][q]);
            *(float2*)(cm + (size_t)row * 128 + colbase + cl * 2) = v;
        }
    }
}

// ---------------------------------------------------------------------------
// SCATTER ∪ KQ ∪ KC merged kernel (scatter hides under node GEMMs).
// Blocks [0,256): scatter -> hiS/wiS/dxS/dyS. [256,+tilesA): kq. Rest: kc.
// ---------------------------------------------------------------------------
__global__ __launch_bounds__(256) void nodes_kernel(
    const int* __restrict__ hi, const int* __restrict__ wi,
    const float* __restrict__ agt_ctrs, const float* __restrict__ ctx_ctrs,
    int* __restrict__ binCtr,
    int* __restrict__ hiS, int* __restrict__ wiS,
    float* __restrict__ dxS, float* __restrict__ dyS,
    const float* __restrict__ agts, const float* __restrict__ ctx,
    const float* __restrict__ q_gw, const float* __restrict__ q_gb,
    const unsigned short* __restrict__ frags,
    float* __restrict__ qm, float* __restrict__ cm,
    int E, int N, int NC, int tilesA)
{
    __shared__ __align__(16) unsigned short sX[32 * SB];
    __shared__ __align__(16) float sY[32 * SF];
    __shared__ float sGw[128], sGb[128];

    const int b = blockIdx.x;
    if (b < 256) {
        for (int i = b * 256 + threadIdx.x; i < E; i += 256 * 256) {
            int h = hi[i], w = wi[i];
            int p = atomicAdd(&binCtr[h], 1);
            hiS[p] = h; wiS[p] = w;
            dxS[p] = agt_ctrs[2 * h]     - ctx_ctrs[2 * w];
            dyS[p] = agt_ctrs[2 * h + 1] - ctx_ctrs[2 * w + 1];
        }
        return;
    }
    int t = b - 256;
    if (t < tilesA)
        kq_tile_body(t, agts, q_gw, q_gb, frags, qm, N, sX, sY, sGw, sGb);
    else
        kc_tile_body(t - tilesA, ctx, frags, cm, NC, sX);
}

// ---------------------------------------------------------------------------
// EDGE (sorted, deferred-W2, bf16 sY, vectorized LDS): 7 barriers/tile.
// launch_bounds MUST stay (256,3): r9 (256,6) and r11 (256,4) both made the
// allocator drop to 40/64 VGPR and spill the weight frags to scratch
// (FETCH 703/394 MB, +60/+50% time). (256,3) -> 84 VGPR, zero spill.
// TILE must stay 32: r13's 64-tile moved qm/cm gathers into the critical
// path (VALUBusy 50->27%, FETCH 2x, edge 120->177 us). Grid 768 = exact
// residency (r15: edge 114.5 -> 111 us).
// ---------------------------------------------------------------------------
__global__ __launch_bounds__(256, 3) void edge_sorted_kernel(
    const int* __restrict__ hiS, const int* __restrict__ wiS,
    const float* __restrict__ dxS, const float* __restrict__ dyS,
    const float* __restrict__ dist_w1, const float* __restrict__ dist_b1,
    const float* __restrict__ dist_gw, const float* __restrict__ dist_gb,
    const float* __restrict__ ctx_gw, const float* __restrict__ ctx_gb,
    const unsigned short* __restrict__ frags,
    const float* __restrict__ qm, const float* __restrict__ cm,
    float* __restrict__ msum, int E, int numTiles)
{
    __shared__ __align__(16) unsigned short sH[32 * SB];   // h1 -> d -> m
    __shared__ __align__(16) unsigned short sYb[32 * SB];  // pre-GN bf16
    __shared__ float sW1[3][128];
    __shared__ float sDGw[128], sDGb[128], sCGw[128], sCGb[128];
    __shared__ int sHiA[32], sWiA[32], sKey[33];
    __shared__ float sDx[32], sDy[32];

    const int tid  = threadIdx.x;
    const int lane = tid & 63;
    const int wv   = tid >> 6;
    const int colbase = wv * 32;
    const int r8 = tid >> 3, c0 = (tid & 7) * 16;
    const int cl = lane & 15, rq = lane >> 4;

    short8 wBh[2][4], wBd[2][4];
    load_bfrags_fast(frags + FRAG_DW2 * FS, wv, lane, wBh);
    load_bfrags_fast(frags + FRAG_W1D * FS, wv, lane, wBd);
    if (tid < 128) {
        sW1[0][tid] = dist_w1[tid];
        sW1[1][tid] = dist_w1[128 + tid];
        sW1[2][tid] = dist_b1[tid];
        sDGw[tid] = dist_gw[tid]; sDGb[tid] = dist_gb[tid];
        sCGw[tid] = ctx_gw[tid];  sCGb[tid] = ctx_gb[tid];
    }

    // prefetch regs for the tile about to be processed
    int ph = 0, pw = 0, pkey = -1; float pdx = 0.f, pdy = 0.f;
    if (tid < 32) {
        pkey = -1 - tid;
        int e = blockIdx.x * 32 + tid;
        if (e < E) { ph = hiS[e]; pw = wiS[e]; pkey = ph; pdx = dxS[e]; pdy = dyS[e]; }
    }

    for (int tile = blockIdx.x; tile < numTiles; tile += gridDim.x) {
        __syncthreads();                                   // (a) prev merge done
        if (tid < 32) {
            sHiA[tid] = ph; sWiA[tid] = pw; sKey[tid] = pkey;
            sDx[tid] = pdx; sDy[tid] = pdy;
        }
        __syncthreads();                                   // (b)

        // prefetch NEXT tile's idx (coalesced, consumed next iteration)
        if (tid < 32) {
            pkey = -1 - tid; ph = 0; pw = 0; pdx = 0.f; pdy = 0.f;
            int tn = tile + gridDim.x;
            if (tn < numTiles) {
                int e = tn * 32 + tid;
                if (e < E) { ph = hiS[e]; pw = wiS[e]; pkey = ph; pdx = dxS[e]; pdy = dyS[e]; }
            }
        }

        // gathers of precomputed qm/cm (permuted: float2 = both cb) — issued
        // EARLY so their latency hides under h1 + GEMM1 + GN (r13 lesson).
        float2 gq[2][4], gc[2][4];
#pragma unroll
        for (int rb = 0; rb < 2; ++rb)
#pragma unroll
        for (int q = 0; q < 4; ++q) {
            int r = rb * 16 + rq * 4 + q;
            gq[rb][q] = *(const float2*)(qm + (size_t)sHiA[r] * 128 + colbase + cl * 2);
            gc[rb][q] = *(const float2*)(cm + (size_t)sWiA[r] * 128 + colbase + cl * 2);
        }

        {   // h1 = relu(dctr @ dist_w1 + b1) -> sH bf16 (vectorized write)
            float dx = sDx[r8], dy = sDy[r8];
            short8 o0, o1;
#pragma unroll
            for (int i = 0; i < 16; ++i) {
                int c = c0 + i;
                float v = fmaf(dx, sW1[0][c], fmaf(dy, sW1[1][c], sW1[2][c]));
                unsigned short u = f2bf(fmaxf(v, 0.f));
                if (i < 8) o0[i] = (short)u; else o1[i - 8] = (short)u;
            }
            short8* dp = (short8*)(sH + r8 * SB + c0);
            dp[0] = o0; dp[1] = o1;
        }
        __syncthreads();                                   // (c)

        f32x4 acc[2][2] = {{{0,0,0,0},{0,0,0,0}},{{0,0,0,0},{0,0,0,0}}};
        mfma_gemm32(sH, wBh, acc, lane);
        {
#pragma unroll
            for (int rb = 0; rb < 2; ++rb)
#pragma unroll
            for (int cb = 0; cb < 2; ++cb)
#pragma unroll
            for (int q = 0; q < 4; ++q)
                sYb[(rb * 16 + rq * 4 + q) * SB + colbase + cb * 16 + cl] = f2bf(acc[rb][cb][q]);
        }
        __syncthreads();                                   // (d) sH reads done
        gn_bf_to_bf16(sYb, sDGw, sDGb, sH, r8, c0);        // d -> sH (reuse)
        __syncthreads();                                   // (e)

        f32x4 a2[2][2];
#pragma unroll
        for (int rb = 0; rb < 2; ++rb)
#pragma unroll
        for (int q = 0; q < 4; ++q) {
            a2[rb][0][q] = gq[rb][q].x + gc[rb][q].x;
            a2[rb][1][q] = gq[rb][q].y + gc[rb][q].y;
        }
        mfma_gemm32(sH, wBd, a2, lane);
        {
#pragma unroll
            for (int rb = 0; rb < 2; ++rb)
#pragma unroll
            for (int cb = 0; cb < 2; ++cb)
#pragma unroll
            for (int q = 0; q < 4; ++q)
                sYb[(rb * 16 + rq * 4 + q) * SB + colbase + cb * 16 + cl] = f2bf(a2[rb][cb][q]);
        }
        __syncthreads();                                   // (f) sH reads done
        gn_bf_to_bf16(sYb, sCGw, sCGb, sH, r8, c0);        // m -> sH
        __syncthreads();                                   // (g)

        {   // coalesced segment merge of m (bf16 in sH) into msum[hi]
            const int col   = tid & 127;
            const int rbase = (tid >> 7) * 16;
            float sum = 0.f;
#pragma unroll
            for (int i = 0; i < 16; ++i) {
                int r = rbase + i;
                sum += bf2f(sH[r * SB + col]);
                bool segEnd = (i == 15) || (sKey[r + 1] != sKey[r]);
                if (segEnd) {
                    int key = sKey[r];
                    if (key >= 0) atomicAdd(&msum[(size_t)key * 128 + col], sum);
                    sum = 0.f;
                }
            }
        }
    }
}

// ---------------------------------------------------------------------------
// FINAL (MFMA, 3 GEMMs): acc = agts@agt_w + msum@ctx_w2;
// x = relu(gn(acc)); out = relu(gn(x @ lin_w) + agts). One tile per block.
// ---------------------------------------------------------------------------
__global__ __launch_bounds__(256) void final_mfma_kernel(
    const float* __restrict__ agts, const float* __restrict__ msum,
    const float* __restrict__ norm_w, const float* __restrict__ norm_b,
    const float* __restrict__ lin_gw, const float* __restrict__ lin_gb,
    const unsigned short* __restrict__ frags,
    float* __restrict__ out, int N)
{
    __shared__ __align__(16) unsigned short sXa[32 * SB];
    __shared__ __align__(16) unsigned short sXm[32 * SB];
    __shared__ float sNw[128], sNb[128], sLw[128], sLb[128];

    const int tid  = threadIdx.x;
    const int lane = tid & 63;
    const int wv   = tid >> 6;
    const int colbase = wv * 32;
    const int r8 = tid >> 3, c0 = (tid & 7) * 16;
    const int cl = lane & 15, rq = lane >> 4;

    short8 wBa[2][4], wB2[2][4], wBl[2][4];
    load_bfrags_fast(frags + FRAG_AGT * FS, wv, lane, wBa);
    load_bfrags_fast(frags + FRAG_CW2 * FS, wv, lane, wB2);
    load_bfrags_fast(frags + FRAG_LIN * FS, wv, lane, wBl);
    if (tid < 128) {
        sNw[tid] = norm_w[tid]; sNb[tid] = norm_b[tid];
        sLw[tid] = lin_gw[tid]; sLb[tid] = lin_gb[tid];
    }

    const int base = blockIdx.x * 32;
    {   // stage bf16(agts) -> sXa, bf16(msum) -> sXm
        int row = base + r8; if (row >= N) row = N - 1;
        const float* sa = agts + (size_t)row * 128 + c0;
        const float* sm = msum + (size_t)row * 128 + c0;
        short8 a0, a1, m0, m1;
#pragma unroll
        for (int i = 0; i < 8; ++i) {
            a0[i] = (short)f2bf(sa[i]); a1[i] = (short)f2bf(sa[i + 8]);
            m0[i] = (short)f2bf(sm[i]); m1[i] = (short)f2bf(sm[i + 8]);
        }
        short8* da = (short8*)(sXa + r8 * SB + c0);
        short8* dm = (short8*)(sXm + r8 * SB + c0);
        da[0] = a0; da[1] = a1; dm[0] = m0; dm[1] = m1;
    }
    __syncthreads();

    f32x4 acc[2][2] = {{{0,0,0,0},{0,0,0,0}},{{0,0,0,0},{0,0,0,0}}};
    mfma_gemm32(sXa, wBa, acc, lane);                      // agts @ agt_w
    mfma_gemm32(sXm, wB2, acc, lane);                      // + msum @ ctx_w2
    __syncthreads();                                       // reads of sXa/sXm done
    {
#pragma unroll
        for (int rb = 0; rb < 2; ++rb)
#pragma unroll
        for (int cb = 0; cb < 2; ++cb)
#pragma unroll
        for (int q = 0; q < 4; ++q)
            sXm[(rb * 16 + rq * 4 + q) * SB + colbase + cb * 16 + cl] = f2bf(acc[rb][cb][q]);
    }
    __syncthreads();
    gn_bf_to_bf16(sXm, sNw, sNb, sXa, r8, c0);             // x -> sXa
    __syncthreads();

    f32x4 aL[2][2] = {{{0,0,0,0},{0,0,0,0}},{{0,0,0,0},{0,0,0,0}}};
    mfma_gemm32(sXa, wBl, aL, lane);
    __syncthreads();
    {
#pragma unroll
        for (int rb = 0; rb < 2; ++rb)
#pragma unroll
        for (int cb = 0; cb < 2; ++cb)
#pragma unroll
        for (int q = 0; q < 4; ++q)
            sXm[(rb * 16 + rq * 4 + q) * SB + colbase + cb * 16 + cl] = f2bf(aL[rb][cb][q]);
    }
    __syncthreads();
    {   // gn(lin) + residual + relu -> out (vectorized LDS reads)
        int row = base + r8;
        if (row < N) {
            const short8* yv = (const short8*)(sXm + r8 * SB + c0);
            short8 a = yv[0], b = yv[1];
            float vals[16]; float s1 = 0.f, s2 = 0.f;
#pragma unroll
            for (int i = 0; i < 8; ++i) {
                vals[i]     = bf2f((unsigned short)a[i]);
                vals[8 + i] = bf2f((unsigned short)b[i]);
            }
#pragma unroll
            for (int i = 0; i < 16; ++i) { s1 += vals[i]; s2 += vals[i] * vals[i]; }
#pragma unroll
            for (int off = 4; off >= 1; off >>= 1) {
                s1 += __shfl_xor(s1, off);
                s2 += __shfl_xor(s2, off);
            }
            float m   = s1 * (1.f / 128.f);
            float var = fmaxf(s2 * (1.f / 128.f) - m * m, 0.f);
            float isc = rsqrtf(var + 1e-5f);
            const float* rp = agts + (size_t)row * 128 + c0;
            float* op = out + (size_t)row * 128 + c0;
#pragma unroll
            for (int i = 0; i < 16; ++i) {
                float y = (vals[i] - m) * isc * sLw[c0 + i] + sLb[c0 + i] + rp[i];
                op[i] = fmaxf(y, 0.f);
            }
        }
    }
}

// ---------------------------------------------------------------------------
// fp32 fallback path (round-1 style), used only if workspace too small
// ---------------------------------------------------------------------------
__device__ __forceinline__ void gemm_tile(const float* __restrict__ sX,
                                          const float* __restrict__ sWT,
                                          int lc, int rg,
                                          float acc0[8], float acc1[8])
{
    const float* w0p = sWT + lc * WSTRIDE;
    const float* w1p = sWT + (lc + 64) * WSTRIDE;
    const float* xp  = sX + rg * 8 * WSTRIDE;
#pragma unroll 4
    for (int k = 0; k < 128; k += 4) {
        float4 w0 = *(const float4*)(w0p + k);
        float4 w1 = *(const float4*)(w1p + k);
#pragma unroll
        for (int j = 0; j < 8; ++j) {
            float4 x = *(const float4*)(xp + j * WSTRIDE + k);
            acc0[j] = fmaf(x.x, w0.x, acc0[j]);
            acc0[j] = fmaf(x.y, w0.y, acc0[j]);
            acc0[j] = fmaf(x.z, w0.z, acc0[j]);
            acc0[j] = fmaf(x.w, w0.w, acc0[j]);
            acc1[j] = fmaf(x.x, w1.x, acc1[j]);
            acc1[j] = fmaf(x.y, w1.y, acc1[j]);
            acc1[j] = fmaf(x.z, w1.z, acc1[j]);
            acc1[j] = fmaf(x.w, w1.w, acc1[j]);
        }
    }
}

__device__ __forceinline__ void stage_wt(const float* __restrict__ W,
                                         float* __restrict__ sWT, int tid)
{
    const int c  = tid & 127;
    const int k0 = tid >> 7;
    float*       dst = sWT + c * WSTRIDE + k0;
    const float* src = W + tid;
    float v[16];
#pragma unroll
    for (int p = 0; p < 4; ++p) {
#pragma unroll
        for (int i = 0; i < 16; ++i) v[i] = src[(p * 16 + i) * 256];
#pragma unroll
        for (int i = 0; i < 16; ++i) dst[(p * 16 + i) * 2] = v[i];
    }
}

__device__ __forceinline__ void gn_rows_lds(const float acc0[8], const float acc1[8],
                                            float gw0, float gw1, float gb0, float gb1,
                                            bool relu, float* __restrict__ dst,
                                            int lc, int rg)
{
#pragma unroll
    for (int j = 0; j < 8; ++j) {
        float s1 = acc0[j] + acc1[j];
        float s2 = acc0[j] * acc0[j] + acc1[j] * acc1[j];
#pragma unroll
        for (int off = 32; off >= 1; off >>= 1) {
            s1 += __shfl_xor(s1, off);
            s2 += __shfl_xor(s2, off);
        }
        float m   = s1 * (1.f / 128.f);
        float var = fmaxf(s2 * (1.f / 128.f) - m * m, 0.f);
        float isc = rsqrtf(var + 1e-5f);
        float y0  = (acc0[j] - m) * isc * gw0 + gb0;
        float y1  = (acc1[j] - m) * isc * gw1 + gb1;
        if (relu) { y0 = fmaxf(y0, 0.f); y1 = fmaxf(y1, 0.f); }
        int r = rg * 8 + j;
        dst[r * WSTRIDE + lc]      = y0;
        dst[r * WSTRIDE + lc + 64] = y1;
    }
}

__global__ __launch_bounds__(256) void rowgemm_kernel(
    const float* __restrict__ X, const float* __restrict__ W,
    float* __restrict__ Y, int n)
{
    __shared__ float sWT[128 * WSTRIDE];
    __shared__ float sX[TILE_E * WSTRIDE];
    const int tid  = threadIdx.x;
    const int base = blockIdx.x * TILE_E;
    {
        int r = tid >> 3, c0 = (tid & 7) * 16;
        int row = base + r;
        if (row < n) {
            const float* src = X + (size_t)row * 128 + c0;
            float*       dst = sX + r * WSTRIDE + c0;
#pragma unroll
            for (int i = 0; i < 4; ++i)
                *(float4*)(dst + i * 4) = *(const float4*)(src + i * 4);
        }
    }
    stage_wt(W, sWT, tid);
    __syncthreads();
    const int lc = tid & 63, rg = tid >> 6;
    float acc0[8] = {0,0,0,0,0,0,0,0}, acc1[8] = {0,0,0,0,0,0,0,0};
    gemm_tile(sX, sWT, lc, rg, acc0, acc1);
#pragma unroll
    for (int j = 0; j < 8; ++j) {
        int row = base + rg * 8 + j;
        if (row < n) {
            Y[(size_t)row * 128 + lc]      = acc0[j];
            Y[(size_t)row * 128 + lc + 64] = acc1[j];
        }
    }
}

__global__ __launch_bounds__(256) void edge_kernel(
    const float* __restrict__ agt_ctrs, const float* __restrict__ ctx_ctrs,
    const int* __restrict__ hi, const int* __restrict__ wi,
    const float* __restrict__ qsrc, const float* __restrict__ ctx,
    const float* __restrict__ dist_w1, const float* __restrict__ dist_b1,
    const float* __restrict__ dist_w2,
    const float* __restrict__ dist_gw, const float* __restrict__ dist_gb,
    const float* __restrict__ q_w,
    const float* __restrict__ q_gw, const float* __restrict__ q_gb,
    const float* __restrict__ ctx_w1,
    const float* __restrict__ ctx_gw, const float* __restrict__ ctx_gb,
    const float* __restrict__ ctx_w2,
    float* __restrict__ out, int E, int numTiles)
{
    __shared__ float sWT[128 * WSTRIDE];
    __shared__ float sH2[TILE_E * WSTRIDE];
    __shared__ float sD2[TILE_E * WSTRIDE];
    __shared__ float sQ2[TILE_E * WSTRIDE];
    __shared__ float sC2[TILE_E * WSTRIDE];
    __shared__ int   sHi[TILE_E];
    __shared__ int   sWiB[TILE_E];
    __shared__ float sDx2[TILE_E], sDy2[TILE_E];

    const int tid = threadIdx.x;
    const int lc = tid & 63, rg = tid >> 6;

    const float dgw0 = dist_gw[lc], dgw1 = dist_gw[lc + 64];
    const float dgb0 = dist_gb[lc], dgb1 = dist_gb[lc + 64];
    const float cgw0 = ctx_gw[lc],  cgw1 = ctx_gw[lc + 64];
    const float cgb0 = ctx_gb[lc],  cgb1 = ctx_gb[lc + 64];
    const float qgw0 = q_gw[lc], qgw1 = q_gw[lc + 64];
    const float qgb0 = q_gb[lc], qgb1 = q_gb[lc + 64];
    const int   hc  = tid & 127;
    const int   hrg = tid >> 7;
    const float w1x = dist_w1[hc], w1y = dist_w1[128 + hc], b1c = dist_b1[hc];

    for (int tile = blockIdx.x; tile < numTiles; tile += gridDim.x) {
        const int base = tile * TILE_E;
        __syncthreads();
        if (tid < TILE_E) {
            int e = base + tid;
            int h = 0, w = 0;
            if (e < E) { h = hi[e]; w = wi[e]; }
            sHi[tid]  = h;
            sWiB[tid] = w;
            sDx2[tid] = agt_ctrs[2 * h]     - ctx_ctrs[2 * w];
            sDy2[tid] = agt_ctrs[2 * h + 1] - ctx_ctrs[2 * w + 1];
        }
        __syncthreads();
        {
            int r = tid >> 3, c0 = (tid & 7) * 16;
            int h = sHi[r], w = sWiB[r];
            const float* qs = qsrc + (size_t)h * 128 + c0;
            const float* cs = ctx  + (size_t)w * 128 + c0;
            float* qd = sQ2 + r * WSTRIDE + c0;
            float* cd = sC2 + r * WSTRIDE + c0;
#pragma unroll
            for (int i = 0; i < 4; ++i) {
                *(float4*)(qd + i * 4) = *(const float4*)(qs + i * 4);
                *(float4*)(cd + i * 4) = *(const float4*)(cs + i * 4);
            }
        }
        {
#pragma unroll
            for (int j = 0; j < 16; ++j) {
                int r = hrg * 16 + j;
                float v = fmaf(sDx2[r], w1x, fmaf(sDy2[r], w1y, b1c));
                sH2[r * WSTRIDE + hc] = fmaxf(v, 0.f);
            }
        }
        __syncthreads();
        stage_wt(q_w, sWT, tid);
        __syncthreads();
        {
            float a0[8] = {0,0,0,0,0,0,0,0}, a1[8] = {0,0,0,0,0,0,0,0};
            gemm_tile(sQ2, sWT, lc, rg, a0, a1);
            __syncthreads();
            gn_rows_lds(a0, a1, qgw0, qgw1, qgb0, qgb1, true, sQ2, lc, rg);
        }
        __syncthreads();
        stage_wt(dist_w2, sWT, tid);
        __syncthreads();
        {
            float a0[8] = {0,0,0,0,0,0,0,0}, a1[8] = {0,0,0,0,0,0,0,0};
            gemm_tile(sH2, sWT, lc, rg, a0, a1);
            gn_rows_lds(a0, a1, dgw0, dgw1, dgb0, dgb1, true, sD2, lc, rg);
        }
        float m0[8] = {0,0,0,0,0,0,0,0}, m1[8] = {0,0,0,0,0,0,0,0};
        __syncthreads();
        stage_wt(ctx_w1, sWT, tid);
        __syncthreads();
        gemm_tile(sD2, sWT, lc, rg, m0, m1);
        __syncthreads();
        stage_wt(ctx_w1 + 128 * 128, sWT, tid);
        __syncthreads();
        gemm_tile(sQ2, sWT, lc, rg, m0, m1);
        __syncthreads();
        stage_wt(ctx_w1 + 2 * 128 * 128, sWT, tid);
        __syncthreads();
        gemm_tile(sC2, sWT, lc, rg, m0, m1);
        gn_rows_lds(m0, m1, cgw0, cgw1, cgb0, cgb1, true, sH2, lc, rg);
        __syncthreads();
        stage_wt(ctx_w2, sWT, tid);
        __syncthreads();
        {
            float a0[8] = {0,0,0,0,0,0,0,0}, a1[8] = {0,0,0,0,0,0,0,0};
            gemm_tile(sH2, sWT, lc, rg, a0, a1);
#pragma unroll
            for (int j = 0; j < 8; ++j) {
                int r = rg * 8 + j;
                int e = base + r;
                if (e < E) {
                    int h = sHi[r];
                    atomicAdd(&out[(size_t)h * 128 + lc],      a0[j]);
                    atomicAdd(&out[(size_t)h * 128 + lc + 64], a1[j]);
                }
            }
        }
    }
}

__global__ __launch_bounds__(256) void final_kernel(
    const float* __restrict__ agts,
    const float* __restrict__ norm_w, const float* __restrict__ norm_b,
    const float* __restrict__ lin_w,
    const float* __restrict__ lin_gw, const float* __restrict__ lin_gb,
    float* __restrict__ out, int n)
{
    __shared__ float sWT[128 * WSTRIDE];
    __shared__ float sX[TILE_E * WSTRIDE];
    const int tid  = threadIdx.x;
    const int base = blockIdx.x * TILE_E;
    {
        int r = tid >> 3, c0 = (tid & 7) * 16;
        int row = base + r;
        if (row < n) {
            const float* src = out + (size_t)row * 128 + c0;
            float vals[16];
            float s1 = 0.f, s2 = 0.f;
#pragma unroll
            for (int i = 0; i < 16; ++i) {
                float v = src[i];
                vals[i] = v; s1 += v; s2 += v * v;
            }
#pragma unroll
            for (int off = 4; off >= 1; off >>= 1) {
                s1 += __shfl_xor(s1, off);
                s2 += __shfl_xor(s2, off);
            }
            float m   = s1 * (1.f / 128.f);
            float var = fmaxf(s2 * (1.f / 128.f) - m * m, 0.f);
            float isc = rsqrtf(var + 1e-5f);
            float* dst = sX + r * WSTRIDE + c0;
#pragma unroll
            for (int i = 0; i < 16; ++i) {
                int c = c0 + i;
                float y = (vals[i] - m) * isc * norm_w[c] + norm_b[c];
                dst[i] = fmaxf(y, 0.f);
            }
        }
    }
    stage_wt(lin_w, sWT, tid);
    __syncthreads();
    const int lc = tid & 63, rg = tid >> 6;
    float acc0[8] = {0,0,0,0,0,0,0,0}, acc1[8] = {0,0,0,0,0,0,0,0};
    gemm_tile(sX, sWT, lc, rg, acc0, acc1);
    const float lgw0 = lin_gw[lc], lgw1 = lin_gw[lc + 64];
    const float lgb0 = lin_gb[lc], lgb1 = lin_gb[lc + 64];
#pragma unroll
    for (int j = 0; j < 8; ++j) {
        float s1 = acc0[j] + acc1[j];
        float s2 = acc0[j] * acc0[j] + acc1[j] * acc1[j];
#pragma unroll
        for (int off = 32; off >= 1; off >>= 1) {
            s1 += __shfl_xor(s1, off);
            s2 += __shfl_xor(s2, off);
        }
        float m   = s1 * (1.f / 128.f);
        float var = fmaxf(s2 * (1.f / 128.f) - m * m, 0.f);
        float isc = rsqrtf(var + 1e-5f);
        int row = base + rg * 8 + j;
        if (row < n) {
            size_t ro = (size_t)row * 128;
            float y0 = (acc0[j] - m) * isc * lgw0 + lgb0 + agts[ro + lc];
            float y1 = (acc1[j] - m) * isc * lgw1 + lgb1 + agts[ro + lc + 64];
            out[ro + lc]      = fmaxf(y0, 0.f);
            out[ro + lc + 64] = fmaxf(y1, 0.f);
        }
    }
}

// ---------------------------------------------------------------------------
extern "C" void kernel_launch(void* const* d_in, const int* in_sizes, int n_in,
                              void* d_out, int out_size, void* d_ws, size_t ws_size,
                              hipStream_t stream)
{
    const float* agts     = (const float*)d_in[0];
    const float* ctx      = (const float*)d_in[1];
    const float* agt_ctrs = (const float*)d_in[2];
    const float* ctx_ctrs = (const float*)d_in[3];
    const int*   hi       = (const int*)d_in[4];
    const int*   wi       = (const int*)d_in[5];
    const float* dist_w1  = (const float*)d_in[6];
    const float* dist_b1  = (const float*)d_in[7];
    const float* dist_w2  = (const float*)d_in[8];
    const float* dist_gw  = (const float*)d_in[9];
    const float* dist_gb  = (const float*)d_in[10];
    const float* q_w      = (const float*)d_in[11];
    const float* q_gw     = (const float*)d_in[12];
    const float* q_gb     = (const float*)d_in[13];
    const float* ctx_w1   = (const float*)d_in[14];
    const float* ctx_gw   = (const float*)d_in[15];
    const float* ctx_gb   = (const float*)d_in[16];
    const float* ctx_w2   = (const float*)d_in[17];
    const float* agt_w    = (const float*)d_in[18];
    const float* norm_w   = (const float*)d_in[19];
    const float* norm_b   = (const float*)d_in[20];
    const float* lin_w    = (const float*)d_in[21];
    const float* lin_gw   = (const float*)d_in[22];
    const float* lin_gb   = (const float*)d_in[23];

    const int N  = in_sizes[0] / 128;   // agents (= bins)
    const int NC = in_sizes[1] / 128;   // ctx nodes
    const int E  = in_sizes[4];
    float* out = (float*)d_out;

    const int tilesA   = (N + 31) / 32;
    const int tilesC   = (NC + 31) / 32;
    const int numTiles = (E + 31) / 32;
    const int nchunks  = (N + 255) / 256;

    const size_t needQM = (size_t)N  * 128 * sizeof(float);
    const size_t needCM = (size_t)NC * 128 * sizeof(float);
    const size_t needMS = (size_t)N  * 128 * sizeof(float);
    const size_t needH  = (size_t)N * sizeof(int);
    const size_t needB  = (size_t)N * sizeof(int);
    const size_t needE4 = (size_t)E * sizeof(int);   // each of hiS/wiS/dxS/dyS
    const size_t needF  = (size_t)8 * FS * sizeof(unsigned short);
    const size_t needSc = 512 * sizeof(int);         // csum (+pad)
    const size_t needTotal = needQM + needCM + needMS + needH + needB
                           + 4 * needE4 + needF + needSc;

    if (ws_size >= needTotal && nchunks <= 256) {
        char* w = (char*)d_ws;
        float*          qm     = (float*)w;            w += needQM;
        float*          cm     = (float*)w;            w += needCM;
        float*          msum   = (float*)w;            w += needMS;   // zeroed
        int*            hist   = (int*)w;              w += needH;    // zeroed
        int*            binCtr = (int*)w;              w += needB;
        int*            hiS    = (int*)w;              w += needE4;
        int*            wiS    = (int*)w;              w += needE4;
        float*          dxS    = (float*)w;            w += needE4;
        float*          dyS    = (float*)w;            w += needE4;
        int*            csum   = (int*)w;              w += 512 * sizeof(int);
        unsigned short* fragsW = (unsigned short*)w;   w += needF;

        // one memset covers msum + hist (adjacent)
        hipMemsetAsync(msum, 0, needMS + needH, stream);

        // L1: prep frags (512 blocks) ∪ hist (256 blocks)
        prep_hist_kernel<<<768, 256, 0, stream>>>(
            dist_w2, ctx_w1, ctx_w2, agt_w, q_w,
            ctx_w1 + 128 * 128, ctx_w1 + 2 * 128 * 128, lin_w, fragsW,
            hi, hist, E);

        // L2/L3: chunk sums, then per-chunk prefix (coff from csum reduce)
        scanA_kernel<<<nchunks, 256, 0, stream>>>(hist, csum, N);
        scanBC_kernel<<<nchunks, 256, 0, stream>>>(hist, csum, binCtr, N, nchunks);

        // L4: scatter (256, hidden under node GEMMs) ∪ kq (tilesA) ∪ kc (tilesC)
        nodes_kernel<<<256 + tilesA + tilesC, 256, 0, stream>>>(
            hi, wi, agt_ctrs, ctx_ctrs, binCtr, hiS, wiS, dxS, dyS,
            agts, ctx, q_gw, q_gb, fragsW, qm, cm,
            E, N, NC, tilesA);

        // L5: edge pipeline over sorted edges -> msum (grid = exact residency)
        int gridE = numTiles < 768 ? numTiles : 768;
        edge_sorted_kernel<<<gridE, 256, 0, stream>>>(
            hiS, wiS, dxS, dyS,
            dist_w1, dist_b1, dist_gw, dist_gb, ctx_gw, ctx_gb,
            fragsW, qm, cm, msum, E, numTiles);

        // L6: final: agts@agt_w + msum@W2 -> norms -> out
        final_mfma_kernel<<<tilesA, 256, 0, stream>>>(
            agts, msum, norm_w, norm_b, lin_gw, lin_gb, fragsW, out, N);
    } else {
        // fp32 fallback (no workspace needed)
        rowgemm_kernel<<<tilesA, 256, 0, stream>>>(agts, agt_w, out, N);
        int gridE = numTiles < 8192 ? numTiles : 8192;
        edge_kernel<<<gridE, 256, 0, stream>>>(agt_ctrs, ctx_ctrs, hi, wi,
            agts, ctx,
            dist_w1, dist_b1, dist_w2, dist_gw, dist_gb,
            q_w, q_gw, q_gb,
            ctx_w1, ctx_gw, ctx_gb, ctx_w2,
            out, E, numTiles);
        final_kernel<<<tilesA, 256, 0, stream>>>(agts, norm_w, norm_b,
            lin_w, lin_gw, lin_gb, out, N);
    }
}